// Round 1
// baseline (20092.107 us; speedup 1.0000x reference)
//
#include <hip/hip_runtime.h>
#include <hip/hip_cooperative_groups.h>

namespace cg = cooperative_groups;

static constexpr int TT = 512, BBATCH = 64, DD = 256, HH = 1024, OOUT = 64;

typedef float f32x4 __attribute__((ext_vector_type(4)));
typedef short bfrag __attribute__((ext_vector_type(8)));

__device__ __forceinline__ float sigm(float x) { return 1.0f / (1.0f + __expf(-x)); }

// fp32 -> bf16 bits, round-to-nearest-even (finite inputs only)
__device__ __forceinline__ unsigned short f2bf(float f) {
    unsigned int u = __builtin_bit_cast(unsigned int, f);
    u += 0x7FFFu + ((u >> 16) & 1u);
    return (unsigned short)(u >> 16);
}

struct Params {
    const float* x; const float* W_real; const float* W_imag;
    const float* U_w; const float* U_b; const float* W_tau_w; const float* W_tau_b;
    const float* mask_real; const float* mask_imag; const float* tau_bias;
    const float* b_real; const float* b_imag; const float* out_w; const float* out_b;
    float* out;             // [T][B][O]
    unsigned short* act;    // ws: [3 mats][2 parity][B][H] bf16
    float* zread;           // ws: [2 parity][B][H] fp32 (zr for readout)
};

// 256 WGs x 512 threads, persistent, one grid.sync per time step.
// WG g: h-tile = (g>>2)*16, b-tile = (g&3)*16.  Readout tile: b=(g&15)*4, o=(g>>4)*4.
__global__ void __launch_bounds__(512, 2) lnn_fused(Params p) {
    extern __shared__ char smem[];
    unsigned short* Wlds = (unsigned short*)smem;                      // [3][16][1024] bf16, swizzled
    unsigned short* Ulds = (unsigned short*)(smem + 3 * 16 * 1024 * 2);// [16][256]  bf16, swizzled
    float* EX = (float*)(smem + 3 * 16 * 1024 * 2 + 16 * 256 * 2);     // [8][256] f32 partials

    const int tid = threadIdx.x;
    const int wave = tid >> 6, lane = tid & 63;
    const int g = blockIdx.x;
    const int h0 = (g >> 2) * 16, b0 = (g & 3) * 16;
    const int ro_b0 = (g & 15) * 4, ro_o0 = (g >> 4) * 4;

    // ---- stage weights into LDS: fold sigmoid(mask), cvt bf16, XOR-swizzle 16B granules ----
    for (int i = tid; i < 3 * 16 * 1024; i += 512) {
        const int mat = i >> 14, r = (i >> 10) & 15, k = i & 1023;
        const int idx = (h0 + r) * HH + k;
        float w;
        if (mat == 0)      w = p.W_real[idx] * sigm(p.mask_real[idx]);
        else if (mat == 1) w = p.W_imag[idx] * sigm(p.mask_imag[idx]);
        else               w = p.W_tau_w[idx];
        const int gk = (k >> 3) ^ (r & 7);
        Wlds[(mat * 16 + r) * 1024 + gk * 8 + (k & 7)] = f2bf(w);
    }
    for (int i = tid; i < 16 * 256; i += 512) {
        const int r = i >> 8, k = i & 255;
        const int gk = (k >> 3) ^ (r & 7);
        Ulds[r * 256 + gk * 8 + (k & 7)] = f2bf(p.U_w[(h0 + r) * DD + k]);
    }

    // ---- per-thread recurrent state + constants (threads 0..255 own one (b,h)) ----
    float zr = 0.f, zi = 0.f, cbr = 0.f, cbi = 0.f, cwtb = 0.f, ctb = 0.f, cub = 0.f;
    int myoff = 0;
    if (tid < 256) {
        const int myb = b0 + (tid >> 4), myh = h0 + (tid & 15);
        myoff = myb * HH + myh;
        cbr = p.b_real[myh]; cbi = p.b_imag[myh];
        cwtb = p.W_tau_b[myh]; ctb = p.tau_bias[myh]; cub = p.U_b[myh];
        // init parity-1 activation buffers (read at t=0): z0 = 0 -> tanh=0, |z|~0
        p.act[(0 * 2 + 1) * BBATCH * HH + myoff] = 0;
        p.act[(1 * 2 + 1) * BBATCH * HH + myoff] = 0;
        p.act[(2 * 2 + 1) * BBATCH * HH + myoff] = 0;
    }

    cg::grid_group gg = cg::this_grid();
    gg.sync();

    for (int t = 0; t <= TT; ++t) {
        const int rp = (t + 1) & 1;  // read parity (acts of state t-1)
        const int wp2 = t & 1;       // write parity (acts of state t)

        if (t < TT && wave < 6) {
            // waves 0..5: mats r/i/tau, each split into two K-halves
            const int mat = wave >> 1, half = wave & 1;
            const int m = lane & 15, kb = lane >> 4, sw = m & 7;
            const unsigned short* actb = p.act + (mat * 2 + rp) * BBATCH * HH + (b0 + m) * HH;
            const unsigned short* wrow = Wlds + (mat * 16 + m) * 1024;
            f32x4 acc = {0.f, 0.f, 0.f, 0.f};
            #pragma unroll
            for (int ks = 0; ks < 16; ++ks) {
                const int k = (half * 16 + ks) * 32 + kb * 8;
                const bfrag a = *(const bfrag*)(actb + k);
                const bfrag b = *(const bfrag*)(wrow + (((k >> 3) ^ sw) << 3));
                acc = __builtin_amdgcn_mfma_f32_16x16x32_bf16(a, b, acc, 0, 0, 0);
            }
            #pragma unroll
            for (int q = 0; q < 4; ++q)
                EX[wave * 256 + (kb * 4 + q) * 16 + m] = acc[q];  // C/D: row=(lane>>4)*4+q, col=lane&15
        } else if (wave == 6 && t < TT) {
            // wave 6: ux = x[t] @ U_w.T  (K = 256), x cvt'd to bf16 on the fly
            const int m = lane & 15, kb = lane >> 4, sw = m & 7;
            const float* xrow = p.x + ((size_t)t * BBATCH + (b0 + m)) * DD;
            const unsigned short* urow = Ulds + m * 256;
            f32x4 acc = {0.f, 0.f, 0.f, 0.f};
            #pragma unroll
            for (int ks = 0; ks < 8; ++ks) {
                const int k = ks * 32 + kb * 8;
                const float4 x0 = *(const float4*)(xrow + k);
                const float4 x1 = *(const float4*)(xrow + k + 4);
                bfrag a;
                a[0] = (short)f2bf(x0.x); a[1] = (short)f2bf(x0.y);
                a[2] = (short)f2bf(x0.z); a[3] = (short)f2bf(x0.w);
                a[4] = (short)f2bf(x1.x); a[5] = (short)f2bf(x1.y);
                a[6] = (short)f2bf(x1.z); a[7] = (short)f2bf(x1.w);
                const bfrag b = *(const bfrag*)(urow + (((k >> 3) ^ sw) << 3));
                acc = __builtin_amdgcn_mfma_f32_16x16x32_bf16(a, b, acc, 0, 0, 0);
            }
            #pragma unroll
            for (int q = 0; q < 4; ++q)
                EX[6 * 256 + (kb * 4 + q) * 16 + m] = acc[q];
        } else if (wave == 7 && t >= 1) {
            // wave 7: exact fp32 readout of y[t-1] from zread (written last step)
            const int r = lane & 15, kq = lane >> 4;
            const int bb = ro_b0 + (r >> 2), oo = ro_o0 + (r & 3);
            const float* zp = p.zread + ((t - 1) & 1) * BBATCH * HH + bb * HH + kq * 256;
            const float* owp = p.out_w + oo * HH + kq * 256;
            float acc = 0.f;
            #pragma unroll 8
            for (int k = 0; k < 256; k += 4) {
                const float4 zv = *(const float4*)(zp + k);
                const float4 wv = *(const float4*)(owp + k);
                acc += zv.x * wv.x + zv.y * wv.y + zv.z * wv.z + zv.w * wv.w;
            }
            acc += __shfl_xor(acc, 16, 64);
            acc += __shfl_xor(acc, 32, 64);
            if (kq == 0)
                p.out[(size_t)(t - 1) * BBATCH * OOUT + bb * OOUT + oo] = acc + p.out_b[oo];
        }

        __syncthreads();

        if (t < TT && tid < 256) {
            const float mr = EX[0 * 256 + tid] + EX[1 * 256 + tid];
            const float mi = EX[2 * 256 + tid] + EX[3 * 256 + tid];
            const float mt = EX[4 * 256 + tid] + EX[5 * 256 + tid];
            const float ux = EX[6 * 256 + tid] + cub;
            const float dr0 = -zr + mr + ux + cbr;
            const float di0 = -zi + mi + ux + cbi;
            float tau = sigm(mt + cwtb) + ctb;
            tau = fminf(fmaxf(tau, 0.01f), 1.0f) + 1e-6f;
            const float dzr = fminf(fmaxf(dr0 / tau, -10.f), 10.f);
            const float dzi = fminf(fmaxf(di0 / tau, -10.f), 10.f);
            zr = fminf(fmaxf(zr + 0.1f * dzr, -100.f), 100.f);
            zi = fminf(fmaxf(zi + 0.1f * dzi, -100.f), 100.f);
            const float ar = tanhf(zr), ai = tanhf(zi);
            const float zm = sqrtf(zr * zr + zi * zi + 1e-20f);
            p.act[(0 * 2 + wp2) * BBATCH * HH + myoff] = f2bf(ar);
            p.act[(1 * 2 + wp2) * BBATCH * HH + myoff] = f2bf(ai);
            p.act[(2 * 2 + wp2) * BBATCH * HH + myoff] = f2bf(zm);
            p.zread[wp2 * BBATCH * HH + myoff] = zr;
        }

        __syncthreads();   // protect EX against next iteration's writes
        gg.sync();         // step boundary: make acts/zread visible grid-wide
    }
}

extern "C" void kernel_launch(void* const* d_in, const int* in_sizes, int n_in,
                              void* d_out, int out_size, void* d_ws, size_t ws_size,
                              hipStream_t stream) {
    Params p;
    p.x         = (const float*)d_in[0];
    p.W_real    = (const float*)d_in[1];
    p.W_imag    = (const float*)d_in[2];
    p.U_w       = (const float*)d_in[3];
    p.U_b       = (const float*)d_in[4];
    p.W_tau_w   = (const float*)d_in[5];
    p.W_tau_b   = (const float*)d_in[6];
    p.mask_real = (const float*)d_in[7];
    p.mask_imag = (const float*)d_in[8];
    p.tau_bias  = (const float*)d_in[9];
    p.b_real    = (const float*)d_in[10];
    p.b_imag    = (const float*)d_in[11];
    p.out_w     = (const float*)d_in[12];
    p.out_b     = (const float*)d_in[13];
    p.out   = (float*)d_out;
    p.act   = (unsigned short*)d_ws;                                  // 786432 B
    p.zread = (float*)((char*)d_ws + 3 * 2 * BBATCH * HH * 2);        // 524288 B

    constexpr unsigned smem = 3 * 16 * 1024 * 2 + 16 * 256 * 2 + 8 * 256 * 4; // 114688 B
    hipFuncSetAttribute(reinterpret_cast<const void*>(lnn_fused),
                        hipFuncAttributeMaxDynamicSharedMemorySize, smem);
    void* args[] = { &p };
    hipLaunchCooperativeKernel(reinterpret_cast<const void*>(lnn_fused),
                               dim3(256), dim3(512), args, smem, stream);
}

// Round 2
// 11292.092 us; speedup vs baseline: 1.7793x; 1.7793x over previous
//
#include <hip/hip_runtime.h>

static constexpr int TT = 512, BBATCH = 64, DD = 256, HH = 1024, OOUT = 64;

typedef float f32x4 __attribute__((ext_vector_type(4)));
typedef short bfrag __attribute__((ext_vector_type(8)));

__device__ __forceinline__ float sigm(float x) { return 1.0f / (1.0f + __expf(-x)); }
__device__ __forceinline__ float tanh_fast(float x) {
    return 1.0f - 2.0f / (__expf(2.0f * x) + 1.0f);   // exact at clip bounds (+/-inf safe)
}

// fp32 -> bf16 bits, round-to-nearest-even (finite inputs only)
__device__ __forceinline__ unsigned short f2bf(float f) {
    unsigned int u = __builtin_bit_cast(unsigned int, f);
    u += 0x7FFFu + ((u >> 16) & 1u);
    return (unsigned short)(u >> 16);
}

struct Params {
    const float* x; const float* W_real; const float* W_imag;
    const float* U_w; const float* U_b; const float* W_tau_w; const float* W_tau_b;
    const float* mask_real; const float* mask_imag; const float* tau_bias;
    const float* b_real; const float* b_imag; const float* out_w; const float* out_b;
    float* out;             // [T][B][O]
    unsigned short* act;    // ws: [3 mats][2 parity][B][H] bf16
    float* zread;           // ws: [2 parity][B][H] fp32 (zr for readout)
    unsigned int* bar;      // ws: 4 group counters, 128B apart (memset to 0 per launch)
};

// 256 WGs x 512 threads, persistent. 4 independent b-groups of 64 WGs; each group
// syncs only among itself (sense-free monotonic counter barrier). With round-robin
// WG->XCD placement, group grp = (blockIdx&7)>>1 occupies XCDs {2g, 2g+1}.
__global__ void __launch_bounds__(512, 2) lnn_fused(Params p) {
    extern __shared__ char smem[];
    unsigned short* Wlds = (unsigned short*)smem;                      // [3][16][1024] bf16, swizzled
    unsigned short* Ulds = (unsigned short*)(smem + 3 * 16 * 1024 * 2);// [16][256]  bf16, swizzled
    float* EX = (float*)(smem + 3 * 16 * 1024 * 2 + 16 * 256 * 2);     // [8][256] f32 partials

    const int tid = threadIdx.x;
    const int wave = tid >> 6, lane = tid & 63;
    const int g = blockIdx.x;
    const int grp = (g & 7) >> 1;                 // b-group 0..3
    const int slot = ((g >> 3) << 1) | (g & 1);   // h-slot 0..63 within group
    const int h0 = slot * 16, b0 = grp * 16;
    // group-local readout tile: 16b x 64o split into 4x16 tiles of 4x4
    const int ro_b0 = b0 + (slot & 3) * 4, ro_o0 = (slot >> 2) * 4;

    // ---- stage weights into LDS: fold sigmoid(mask), cvt bf16, XOR-swizzle 16B granules ----
    for (int i = tid; i < 3 * 16 * 1024; i += 512) {
        const int mat = i >> 14, r = (i >> 10) & 15, k = i & 1023;
        const int idx = (h0 + r) * HH + k;
        float w;
        if (mat == 0)      w = p.W_real[idx] * sigm(p.mask_real[idx]);
        else if (mat == 1) w = p.W_imag[idx] * sigm(p.mask_imag[idx]);
        else               w = p.W_tau_w[idx];
        const int gk = (k >> 3) ^ (r & 7);
        Wlds[(mat * 16 + r) * 1024 + gk * 8 + (k & 7)] = f2bf(w);
    }
    for (int i = tid; i < 16 * 256; i += 512) {
        const int r = i >> 8, k = i & 255;
        const int gk = (k >> 3) ^ (r & 7);
        Ulds[r * 256 + gk * 8 + (k & 7)] = f2bf(p.U_w[(h0 + r) * DD + k]);
    }

    // ---- per-thread recurrent state + constants (threads 0..255 own one (b,h)) ----
    float zr = 0.f, zi = 0.f, cbr = 0.f, cbi = 0.f, cwtb = 0.f, ctb = 0.f, cub = 0.f;
    int myoff = 0;
    if (tid < 256) {
        const int myb = b0 + (tid >> 4), myh = h0 + (tid & 15);
        myoff = myb * HH + myh;
        cbr = p.b_real[myh]; cbi = p.b_imag[myh];
        cwtb = p.W_tau_b[myh]; ctb = p.tau_bias[myh]; cub = p.U_b[myh];
        // init parity-1 activation buffers (read at t=0): z0 = 0 -> tanh=0, |z|~0
        p.act[(0 * 2 + 1) * BBATCH * HH + myoff] = 0;
        p.act[(1 * 2 + 1) * BBATCH * HH + myoff] = 0;
        p.act[(2 * 2 + 1) * BBATCH * HH + myoff] = 0;
    }

    unsigned int* bar = p.bar + grp * 32;  // 128B-separated counters
    auto group_barrier = [&](unsigned int gen) {
        __syncthreads();                   // all WG stores drained (vmcnt 0) before fence
        if (tid == 0) {
            __threadfence();               // release: wbl2 -> group-visible via L3
            atomicAdd(bar, 1u);
            const unsigned int tgt = 64u * gen;
            while (__hip_atomic_load(bar, __ATOMIC_RELAXED, __HIP_MEMORY_SCOPE_AGENT) < tgt)
                __builtin_amdgcn_s_sleep(1);
            __threadfence();               // acquire: inv -> see peers' fresh lines
        }
        __syncthreads();
    };

    group_barrier(1);                      // init acts visible group-wide

    for (int t = 0; t <= TT; ++t) {
        const int rp = (t + 1) & 1;  // read parity (acts of state t-1)
        const int wp2 = t & 1;       // write parity (acts of state t)

        if (t < TT && wave < 6) {
            // waves 0..5: mats r/i/tau, each split into two K-halves
            const int mat = wave >> 1, half = wave & 1;
            const int m = lane & 15, kb = lane >> 4, sw = m & 7;
            const unsigned short* actb = p.act + (mat * 2 + rp) * BBATCH * HH + (b0 + m) * HH;
            const unsigned short* wrow = Wlds + (mat * 16 + m) * 1024;
            f32x4 acc = {0.f, 0.f, 0.f, 0.f};
            #pragma unroll
            for (int ks = 0; ks < 16; ++ks) {
                const int k = (half * 16 + ks) * 32 + kb * 8;
                const bfrag a = *(const bfrag*)(actb + k);
                const bfrag b = *(const bfrag*)(wrow + (((k >> 3) ^ sw) << 3));
                acc = __builtin_amdgcn_mfma_f32_16x16x32_bf16(a, b, acc, 0, 0, 0);
            }
            #pragma unroll
            for (int q = 0; q < 4; ++q)
                EX[wave * 256 + (kb * 4 + q) * 16 + m] = acc[q];  // C/D: row=(lane>>4)*4+q, col=lane&15
        } else if (wave == 6 && t < TT) {
            // wave 6: ux = x[t] @ U_w.T  (K = 256), x cvt'd to bf16 on the fly
            const int m = lane & 15, kb = lane >> 4, sw = m & 7;
            const float* xrow = p.x + ((size_t)t * BBATCH + (b0 + m)) * DD;
            const unsigned short* urow = Ulds + m * 256;
            f32x4 acc = {0.f, 0.f, 0.f, 0.f};
            #pragma unroll
            for (int ks = 0; ks < 8; ++ks) {
                const int k = ks * 32 + kb * 8;
                const float4 x0 = *(const float4*)(xrow + k);
                const float4 x1 = *(const float4*)(xrow + k + 4);
                bfrag a;
                a[0] = (short)f2bf(x0.x); a[1] = (short)f2bf(x0.y);
                a[2] = (short)f2bf(x0.z); a[3] = (short)f2bf(x0.w);
                a[4] = (short)f2bf(x1.x); a[5] = (short)f2bf(x1.y);
                a[6] = (short)f2bf(x1.z); a[7] = (short)f2bf(x1.w);
                const bfrag b = *(const bfrag*)(urow + (((k >> 3) ^ sw) << 3));
                acc = __builtin_amdgcn_mfma_f32_16x16x32_bf16(a, b, acc, 0, 0, 0);
            }
            #pragma unroll
            for (int q = 0; q < 4; ++q)
                EX[6 * 256 + (kb * 4 + q) * 16 + m] = acc[q];
        } else if (wave == 7 && t >= 1) {
            // wave 7: exact fp32 readout of y[t-1] from zread (written last step, own group rows)
            const int r = lane & 15, kq = lane >> 4;
            const int bb = ro_b0 + (r >> 2), oo = ro_o0 + (r & 3);
            const float* zp = p.zread + ((t - 1) & 1) * BBATCH * HH + bb * HH + kq * 256;
            const float* owp = p.out_w + oo * HH + kq * 256;
            float acc = 0.f;
            #pragma unroll 8
            for (int k = 0; k < 256; k += 4) {
                const float4 zv = *(const float4*)(zp + k);
                const float4 wv = *(const float4*)(owp + k);
                acc += zv.x * wv.x + zv.y * wv.y + zv.z * wv.z + zv.w * wv.w;
            }
            acc += __shfl_xor(acc, 16, 64);
            acc += __shfl_xor(acc, 32, 64);
            if (kq == 0)
                p.out[(size_t)(t - 1) * BBATCH * OOUT + bb * OOUT + oo] = acc + p.out_b[oo];
        }

        __syncthreads();

        if (t < TT && tid < 256) {
            const float mr = EX[0 * 256 + tid] + EX[1 * 256 + tid];
            const float mi = EX[2 * 256 + tid] + EX[3 * 256 + tid];
            const float mt = EX[4 * 256 + tid] + EX[5 * 256 + tid];
            const float ux = EX[6 * 256 + tid] + cub;
            const float dr0 = -zr + mr + ux + cbr;
            const float di0 = -zi + mi + ux + cbi;
            float tau = sigm(mt + cwtb) + ctb;
            tau = fminf(fmaxf(tau, 0.01f), 1.0f) + 1e-6f;
            const float dzr = fminf(fmaxf(dr0 / tau, -10.f), 10.f);
            const float dzi = fminf(fmaxf(di0 / tau, -10.f), 10.f);
            zr = fminf(fmaxf(zr + 0.1f * dzr, -100.f), 100.f);
            zi = fminf(fmaxf(zi + 0.1f * dzi, -100.f), 100.f);
            const float ar = tanh_fast(zr), ai = tanh_fast(zi);
            const float zm = sqrtf(zr * zr + zi * zi + 1e-20f);
            p.act[(0 * 2 + wp2) * BBATCH * HH + myoff] = f2bf(ar);
            p.act[(1 * 2 + wp2) * BBATCH * HH + myoff] = f2bf(ai);
            p.act[(2 * 2 + wp2) * BBATCH * HH + myoff] = f2bf(zm);
            p.zread[wp2 * BBATCH * HH + myoff] = zr;
        }

        if (t < TT) group_barrier(t + 2);  // step boundary for this b-group only
    }
}

extern "C" void kernel_launch(void* const* d_in, const int* in_sizes, int n_in,
                              void* d_out, int out_size, void* d_ws, size_t ws_size,
                              hipStream_t stream) {
    Params p;
    p.x         = (const float*)d_in[0];
    p.W_real    = (const float*)d_in[1];
    p.W_imag    = (const float*)d_in[2];
    p.U_w       = (const float*)d_in[3];
    p.U_b       = (const float*)d_in[4];
    p.W_tau_w   = (const float*)d_in[5];
    p.W_tau_b   = (const float*)d_in[6];
    p.mask_real = (const float*)d_in[7];
    p.mask_imag = (const float*)d_in[8];
    p.tau_bias  = (const float*)d_in[9];
    p.b_real    = (const float*)d_in[10];
    p.b_imag    = (const float*)d_in[11];
    p.out_w     = (const float*)d_in[12];
    p.out_b     = (const float*)d_in[13];
    p.out   = (float*)d_out;
    p.act   = (unsigned short*)d_ws;                                  // 786432 B
    p.zread = (float*)((char*)d_ws + 3 * 2 * BBATCH * HH * 2);        // 524288 B
    p.bar   = (unsigned int*)((char*)d_ws + 1310720);                 // 512 B

    hipMemsetAsync((char*)d_ws + 1310720, 0, 512, stream);            // reset barrier counters

    constexpr unsigned smem = 3 * 16 * 1024 * 2 + 16 * 256 * 2 + 8 * 256 * 4; // 114688 B
    hipFuncSetAttribute(reinterpret_cast<const void*>(lnn_fused),
                        hipFuncAttributeMaxDynamicSharedMemorySize, smem);
    void* args[] = { &p };
    hipLaunchCooperativeKernel(reinterpret_cast<const void*>(lnn_fused),
                               dim3(256), dim3(512), args, smem, stream);
}

// Round 5
// 5109.509 us; speedup vs baseline: 3.9323x; 2.2100x over previous
//
#include <hip/hip_runtime.h>

static constexpr int TT = 512, BBATCH = 64, DD = 256, HH = 1024, OOUT = 64;

typedef float f32x4 __attribute__((ext_vector_type(4)));
typedef short bfrag __attribute__((ext_vector_type(8)));

__device__ __forceinline__ float sigm(float x) { return 1.0f / (1.0f + __expf(-x)); }
__device__ __forceinline__ float tanh_fast(float x) {
    return 1.0f - 2.0f / (__expf(2.0f * x) + 1.0f);   // exact at clip bounds
}
// fp32 -> bf16 bits, round-to-nearest-even (finite inputs only)
__device__ __forceinline__ unsigned short f2bf(float f) {
    unsigned int u = __builtin_bit_cast(unsigned int, f);
    u += 0x7FFFu + ((u >> 16) & 1u);
    return (unsigned short)(u >> 16);
}

struct Params {
    const float *x, *W_real, *W_imag, *U_w, *U_b, *W_tau_w, *W_tau_b,
                *mask_real, *mask_imag, *tau_bias, *b_real, *b_imag, *out_w, *out_b;
    float* out;             // [T][B][O]
    unsigned short* act;    // ws: [3 mats][2 parity][B][H] bf16
    float* zread;           // ws: [2 parity][B][H] f32
    unsigned int* bar;      // ws: 4 group counters, 128B apart (memset to 0 per launch)
};

// Device-coherent load: bypass L1+L2, served at LLC (Infinity Cache).
#define LDC(v_, p_, o_) asm volatile("global_load_dwordx4 %0, %1, off offset:" #o_ " sc0 sc1" \
                                     : "=v"(v_) : "v"(p_))
#define WAITV(n_) do { asm volatile("s_waitcnt vmcnt(" #n_ ")" ::: "memory"); \
                       __builtin_amdgcn_sched_barrier(0); } while (0)
#define MFMA(a_, b_, c_) __builtin_amdgcn_mfma_f32_16x16x32_bf16(a_, b_, c_, 0, 0, 0)
// Device-coherent store (write-through, no local-L2 dirty allocate).
#define STC(p_, v_) __hip_atomic_store((p_), (v_), __ATOMIC_RELAXED, __HIP_MEMORY_SCOPE_AGENT)

// 256 WGs x 512 threads, 1 WG/CU (LDS 114688B), persistent, cooperative.
// 4 b-groups of 64 WGs (blockIdx-derived -> group size exact by construction).
// Cross-WG state flows through LLC via sc0+sc1 accesses; zero threadfence.
__global__ void __launch_bounds__(512, 2) lnn_fused(Params p) {
    extern __shared__ char smem[];
    unsigned short* Wlds = (unsigned short*)smem;                      // [3][16][1024] bf16, swizzled
    unsigned short* Ulds = (unsigned short*)(smem + 3 * 16 * 1024 * 2);// [16][256]  bf16, swizzled
    float* EX = (float*)(smem + 3 * 16 * 1024 * 2 + 16 * 256 * 2);     // [8][256] f32 partials

    const int tid = threadIdx.x;
    const int wave = tid >> 6, lane = tid & 63;
    const int g = blockIdx.x;
    const int grp = (g & 7) >> 1;                 // b-group 0..3 (64 WGs each)
    const int slot = ((g >> 3) << 1) | (g & 1);   // h-slot 0..63 within group
    const int h0 = slot * 16, b0 = grp * 16;
    const int ro_b0 = b0 + (slot & 3) * 4, ro_o0 = (slot >> 2) * 4;

    // ---- stage weights into LDS: fold sigmoid(mask), cvt bf16, XOR-swizzle 16B granules ----
    for (int i = tid; i < 3 * 16 * 1024; i += 512) {
        const int mat = i >> 14, r = (i >> 10) & 15, k = i & 1023;
        const int idx = (h0 + r) * HH + k;
        float w;
        if (mat == 0)      w = p.W_real[idx] * sigm(p.mask_real[idx]);
        else if (mat == 1) w = p.W_imag[idx] * sigm(p.mask_imag[idx]);
        else               w = p.W_tau_w[idx];
        const int gk = (k >> 3) ^ (r & 7);
        Wlds[(mat * 16 + r) * 1024 + gk * 8 + (k & 7)] = f2bf(w);
    }
    for (int i = tid; i < 16 * 256; i += 512) {
        const int r = i >> 8, k = i & 255;
        const int gk = (k >> 3) ^ (r & 7);
        Ulds[r * 256 + gk * 8 + (k & 7)] = f2bf(p.U_w[(h0 + r) * DD + k]);
    }

    // ---- per-thread recurrent state + constants (threads 0..255 own one (b,h)) ----
    float zr = 0.f, zi = 0.f, cbr = 0.f, cbi = 0.f, cwtb = 0.f, ctb = 0.f, cub = 0.f;
    int myoff = 0;
    if (tid < 256) {
        const int myb = b0 + (tid >> 4), myh = h0 + (tid & 15);
        myoff = myb * HH + myh;
        cbr = p.b_real[myh]; cbi = p.b_imag[myh];
        cwtb = p.W_tau_b[myh]; ctb = p.tau_bias[myh]; cub = p.U_b[myh];
        // init parity-1 activation buffers (read at t=0): z0 = 0 -> tanh=0, |z|~0
        STC(p.act + (0 * 2 + 1) * BBATCH * HH + myoff, (unsigned short)0);
        STC(p.act + (1 * 2 + 1) * BBATCH * HH + myoff, (unsigned short)0);
        STC(p.act + (2 * 2 + 1) * BBATCH * HH + myoff, (unsigned short)0);
    }

    unsigned int* bar = p.bar + grp * 32;  // 128B-separated counters
    auto group_barrier = [&](unsigned int gen) {
        __syncthreads();                   // vmcnt(0): all write-through stores at LLC
        if (tid == 0) {
            __hip_atomic_fetch_add(bar, 1u, __ATOMIC_RELAXED, __HIP_MEMORY_SCOPE_AGENT);
            const unsigned int tgt = 64u * gen;
            int guard = 1 << 20;           // bounded spin: never hang the harness
            while (__hip_atomic_load(bar, __ATOMIC_RELAXED, __HIP_MEMORY_SCOPE_AGENT) < tgt
                   && --guard)
                __builtin_amdgcn_s_sleep(1);
        }
        __syncthreads();
    };

    group_barrier(1);                      // init acts visible device-wide

    for (int t = 0; t <= TT; ++t) {
        const int rp = (t + 1) & 1;  // read parity (acts of state t-1)
        const int wp2 = t & 1;       // write parity (acts of state t)

        if (t < TT && wave < 6) {
            // waves 0..5: mats r/i/tau, each split into two K-halves
            const int mat = wave >> 1, half = wave & 1;
            const int m = lane & 15, kb = lane >> 4, sw = m & 7;
            const unsigned short* aptr = p.act + (mat * 2 + rp) * BBATCH * HH
                                         + (b0 + m) * HH + half * 512 + kb * 8;
            bfrag a0,a1,a2,a3,a4,a5,a6,a7,a8,a9,a10,a11,a12,a13,a14,a15;
            LDC(a0,aptr,0);    LDC(a1,aptr,64);   LDC(a2,aptr,128);  LDC(a3,aptr,192);
            LDC(a4,aptr,256);  LDC(a5,aptr,320);  LDC(a6,aptr,384);  LDC(a7,aptr,448);
            LDC(a8,aptr,512);  LDC(a9,aptr,576);  LDC(a10,aptr,640); LDC(a11,aptr,704);
            LDC(a12,aptr,768); LDC(a13,aptr,832); LDC(a14,aptr,896); LDC(a15,aptr,960);
            f32x4 acc = {0.f, 0.f, 0.f, 0.f};
            const unsigned short* wrow = Wlds + (mat * 16 + m) * 1024;
            #define STW(ks_, av_) acc = MFMA(av_, *(const bfrag*)(wrow + \
                ((((half << 6) + ((ks_) << 2) + kb) ^ sw) << 3)), acc);
            WAITV(8);
            STW(0,a0) STW(1,a1) STW(2,a2) STW(3,a3)
            STW(4,a4) STW(5,a5) STW(6,a6) STW(7,a7)
            WAITV(0);
            STW(8,a8) STW(9,a9) STW(10,a10) STW(11,a11)
            STW(12,a12) STW(13,a13) STW(14,a14) STW(15,a15)
            #undef STW
            #pragma unroll
            for (int q = 0; q < 4; ++q)
                EX[wave * 256 + (kb * 4 + q) * 16 + m] = acc[q];  // C/D: row=(lane>>4)*4+q, col=m
        } else if (wave == 6 && t < TT) {
            // wave 6: ux = x[t] @ U_w.T (K=256); x is read-only input -> plain loads
            const int m = lane & 15, kb = lane >> 4, sw = m & 7;
            const float* xrow = p.x + ((size_t)t * BBATCH + (b0 + m)) * DD;
            const unsigned short* urow = Ulds + m * 256;
            f32x4 acc = {0.f, 0.f, 0.f, 0.f};
            #pragma unroll
            for (int ks = 0; ks < 8; ++ks) {
                const int k = ks * 32 + kb * 8;
                const f32x4 x0 = *(const f32x4*)(xrow + k);
                const f32x4 x1 = *(const f32x4*)(xrow + k + 4);
                bfrag a;
                a[0]=(short)f2bf(x0[0]); a[1]=(short)f2bf(x0[1]);
                a[2]=(short)f2bf(x0[2]); a[3]=(short)f2bf(x0[3]);
                a[4]=(short)f2bf(x1[0]); a[5]=(short)f2bf(x1[1]);
                a[6]=(short)f2bf(x1[2]); a[7]=(short)f2bf(x1[3]);
                const bfrag b = *(const bfrag*)(urow + (((ks * 4 + kb) ^ sw) << 3));
                acc = MFMA(a, b, acc);
            }
            #pragma unroll
            for (int q = 0; q < 4; ++q)
                EX[6 * 256 + (kb * 4 + q) * 16 + m] = acc[q];
        } else if (wave == 7 && t >= 1) {
            // wave 7: exact fp32 readout of y[t-1]; zread via device-coherent loads
            const int r = lane & 15, kq = lane >> 4;
            const int bb = ro_b0 + (r >> 2), oo = ro_o0 + (r & 3);
            const float* zp = p.zread + ((t - 1) & 1) * BBATCH * HH + bb * HH + kq * 256;
            const float* owp = p.out_w + oo * HH + kq * 256;
            float acc = 0.f;
            #define RB(bt_) { \
                const float* zq = zp + (bt_) * 64; \
                f32x4 z0,z1,z2,z3,z4,z5,z6,z7,z8,z9,z10,z11,z12,z13,z14,z15; \
                LDC(z0,zq,0);    LDC(z1,zq,16);   LDC(z2,zq,32);   LDC(z3,zq,48); \
                LDC(z4,zq,64);   LDC(z5,zq,80);   LDC(z6,zq,96);   LDC(z7,zq,112); \
                LDC(z8,zq,128);  LDC(z9,zq,144);  LDC(z10,zq,160); LDC(z11,zq,176); \
                LDC(z12,zq,192); LDC(z13,zq,208); LDC(z14,zq,224); LDC(z15,zq,240); \
                WAITV(0); \
                const f32x4* wq = (const f32x4*)(owp + (bt_) * 64); \
                acc += z0[0]*wq[0][0]+z0[1]*wq[0][1]+z0[2]*wq[0][2]+z0[3]*wq[0][3]; \
                acc += z1[0]*wq[1][0]+z1[1]*wq[1][1]+z1[2]*wq[1][2]+z1[3]*wq[1][3]; \
                acc += z2[0]*wq[2][0]+z2[1]*wq[2][1]+z2[2]*wq[2][2]+z2[3]*wq[2][3]; \
                acc += z3[0]*wq[3][0]+z3[1]*wq[3][1]+z3[2]*wq[3][2]+z3[3]*wq[3][3]; \
                acc += z4[0]*wq[4][0]+z4[1]*wq[4][1]+z4[2]*wq[4][2]+z4[3]*wq[4][3]; \
                acc += z5[0]*wq[5][0]+z5[1]*wq[5][1]+z5[2]*wq[5][2]+z5[3]*wq[5][3]; \
                acc += z6[0]*wq[6][0]+z6[1]*wq[6][1]+z6[2]*wq[6][2]+z6[3]*wq[6][3]; \
                acc += z7[0]*wq[7][0]+z7[1]*wq[7][1]+z7[2]*wq[7][2]+z7[3]*wq[7][3]; \
                acc += z8[0]*wq[8][0]+z8[1]*wq[8][1]+z8[2]*wq[8][2]+z8[3]*wq[8][3]; \
                acc += z9[0]*wq[9][0]+z9[1]*wq[9][1]+z9[2]*wq[9][2]+z9[3]*wq[9][3]; \
                acc += z10[0]*wq[10][0]+z10[1]*wq[10][1]+z10[2]*wq[10][2]+z10[3]*wq[10][3]; \
                acc += z11[0]*wq[11][0]+z11[1]*wq[11][1]+z11[2]*wq[11][2]+z11[3]*wq[11][3]; \
                acc += z12[0]*wq[12][0]+z12[1]*wq[12][1]+z12[2]*wq[12][2]+z12[3]*wq[12][3]; \
                acc += z13[0]*wq[13][0]+z13[1]*wq[13][1]+z13[2]*wq[13][2]+z13[3]*wq[13][3]; \
                acc += z14[0]*wq[14][0]+z14[1]*wq[14][1]+z14[2]*wq[14][2]+z14[3]*wq[14][3]; \
                acc += z15[0]*wq[15][0]+z15[1]*wq[15][1]+z15[2]*wq[15][2]+z15[3]*wq[15][3]; }
            RB(0) RB(1) RB(2) RB(3)
            #undef RB
            acc += __shfl_xor(acc, 16, 64);
            acc += __shfl_xor(acc, 32, 64);
            if (kq == 0)
                p.out[(size_t)(t - 1) * BBATCH * OOUT + bb * OOUT + oo] = acc + p.out_b[oo];
        }

        __syncthreads();

        if (t < TT && tid < 256) {
            const float mr = EX[0 * 256 + tid] + EX[1 * 256 + tid];
            const float mi = EX[2 * 256 + tid] + EX[3 * 256 + tid];
            const float mt = EX[4 * 256 + tid] + EX[5 * 256 + tid];
            const float ux = EX[6 * 256 + tid] + cub;
            const float dr0 = -zr + mr + ux + cbr;
            const float di0 = -zi + mi + ux + cbi;
            float tau = sigm(mt + cwtb) + ctb;
            tau = fminf(fmaxf(tau, 0.01f), 1.0f) + 1e-6f;
            const float dzr = fminf(fmaxf(dr0 / tau, -10.f), 10.f);
            const float dzi = fminf(fmaxf(di0 / tau, -10.f), 10.f);
            zr = fminf(fmaxf(zr + 0.1f * dzr, -100.f), 100.f);
            zi = fminf(fmaxf(zi + 0.1f * dzi, -100.f), 100.f);
            const float ar = tanh_fast(zr), ai = tanh_fast(zi);
            const float zm = sqrtf(zr * zr + zi * zi + 1e-20f);
            STC(p.act + (0 * 2 + wp2) * BBATCH * HH + myoff, f2bf(ar));
            STC(p.act + (1 * 2 + wp2) * BBATCH * HH + myoff, f2bf(ai));
            STC(p.act + (2 * 2 + wp2) * BBATCH * HH + myoff, f2bf(zm));
            STC(p.zread + wp2 * BBATCH * HH + myoff, zr);
        }

        if (t < TT) group_barrier(t + 2);  // step boundary for this b-group only
    }
}

extern "C" void kernel_launch(void* const* d_in, const int* in_sizes, int n_in,
                              void* d_out, int out_size, void* d_ws, size_t ws_size,
                              hipStream_t stream) {
    Params p;
    p.x         = (const float*)d_in[0];
    p.W_real    = (const float*)d_in[1];
    p.W_imag    = (const float*)d_in[2];
    p.U_w       = (const float*)d_in[3];
    p.U_b       = (const float*)d_in[4];
    p.W_tau_w   = (const float*)d_in[5];
    p.W_tau_b   = (const float*)d_in[6];
    p.mask_real = (const float*)d_in[7];
    p.mask_imag = (const float*)d_in[8];
    p.tau_bias  = (const float*)d_in[9];
    p.b_real    = (const float*)d_in[10];
    p.b_imag    = (const float*)d_in[11];
    p.out_w     = (const float*)d_in[12];
    p.out_b     = (const float*)d_in[13];
    p.out   = (float*)d_out;
    p.act   = (unsigned short*)d_ws;                          // 786432 B
    p.zread = (float*)((char*)d_ws + 786432);                 // 524288 B
    p.bar   = (unsigned int*)((char*)d_ws + 1310720);         // 512 B

    hipMemsetAsync((char*)d_ws + 1310720, 0, 512, stream);    // reset barrier counters

    constexpr unsigned smem = 3 * 16 * 1024 * 2 + 16 * 256 * 2 + 8 * 256 * 4; // 114688 B
    hipFuncSetAttribute(reinterpret_cast<const void*>(lnn_fused),
                        hipFuncAttributeMaxDynamicSharedMemorySize, smem);
    void* args[] = { &p };
    hipLaunchCooperativeKernel(reinterpret_cast<const void*>(lnn_fused),
                               dim3(256), dim3(512), args, smem, stream);
}